// Round 5
// baseline (124.881 us; speedup 1.0000x reference)
//
#include <hip/hip_runtime.h>
#include <math.h>

#define HH 512
#define WW 512
#define NA 180
#define ND 729
#define NB 2

// ws layout (float units):
//   [0]                completion counter (memset to 0 each launch)
//   [1024, 1024+360)   interleaved {cos,sin} per angle
//   [2048 + b*192)     P0[b][0..180]   (exclusive prefix of f[b][a][0])
//   [2560 + b*192)     P728[b][0..180] (exclusive prefix of f[b][a][728])
//   [4096, ...)        filtered sinograms
#define WS_CS 1024
#define WS_P0 2048
#define WS_P728 2560
#define WS_FILT 4096

// Filter kernel (closed form):
//   g[n] = (0.125 + min(n, D-n)/1458) / 729   (tail of truncated odd-k sum < 7e-8/tap)
__device__ __forceinline__ float g_of(int n) {
    int m = n < (ND - n) ? n : (ND - n);
    return (float)((0.125 + (double)m * (1.0 / 1458.0)) * (1.0 / 729.0));
}

// Circular convolution, register-blocked 4 outputs x 4 m's, 2 rows per block
// (shared ga image + g-window reads). Block 180 does angle tables. The last
// data block to finish also computes the P0/P728 prefix sums (last-block-done
// pattern: device-scope fence + atomic counter, counter memset to 0 on stream).
__global__ __launch_bounds__(192) void k_filter(const float* __restrict__ sino,
                                                float* __restrict__ ws) {
    int blk = blockIdx.x;
    int tid = threadIdx.x;
    if (blk == 180) {
        for (int t = tid; t < NA; t += 192) {
            double ang = M_PI * (double)t / (double)(NA - 1);
            ws[WS_CS + 2 * t] = (float)cos(ang);
            ws[WS_CS + 2 * t + 1] = (float)sin(ang);
        }
        return;
    }
    __shared__ float xs0[736], xs1[736];
    __shared__ float ga[1464];   // ga[i] = g[(i+727) mod D]
    __shared__ int last;
    int row0 = 2 * blk;          // rows row0, row0+1
    const float* x0 = sino + row0 * ND;
    const float* x1 = x0 + ND;
    for (int i = tid; i < 736; i += 192) {
        bool in = i < ND;
        xs0[i] = in ? x0[i] : 0.0f;
        xs1[i] = in ? x1[i] : 0.0f;
    }
    for (int i = tid; i < 1464; i += 192) ga[i] = g_of((i + 727) % ND);
    __syncthreads();
    int t = (tid < 183) ? tid : 0;
    int n = 4 * t;
    float a0 = 0.f, a1 = 0.f, a2 = 0.f, a3 = 0.f;
    float b0 = 0.f, b1 = 0.f, b2 = 0.f, b3 = 0.f;
    #pragma unroll 4
    for (int m = 0; m < ND; m += 4) {
        float4 xv = *(const float4*)&xs0[m];
        float4 yv = *(const float4*)&xs1[m];
        int B = n - m + 728;
        float4 gA = *(const float4*)&ga[B];
        float4 gB = *(const float4*)&ga[B + 4];
        a0 += xv.x * gA.w + xv.y * gA.z + xv.z * gA.y + xv.w * gA.x;
        a1 += xv.x * gB.x + xv.y * gA.w + xv.z * gA.z + xv.w * gA.y;
        a2 += xv.x * gB.y + xv.y * gB.x + xv.z * gA.w + xv.w * gA.z;
        a3 += xv.x * gB.z + xv.y * gB.y + xv.z * gB.x + xv.w * gA.w;
        b0 += yv.x * gA.w + yv.y * gA.z + yv.z * gA.y + yv.w * gA.x;
        b1 += yv.x * gB.x + yv.y * gA.w + yv.z * gA.z + yv.w * gA.y;
        b2 += yv.x * gB.y + yv.y * gB.x + yv.z * gA.w + yv.w * gA.z;
        b3 += yv.x * gB.z + yv.y * gB.y + yv.z * gB.x + yv.w * gA.w;
    }
    if (tid < 183) {
        float* f0 = ws + WS_FILT + row0 * ND;
        float* f1 = f0 + ND;
        f0[n] = a0;
        f1[n] = b0;
        if (n + 1 < ND) { f0[n + 1] = a1; f1[n + 1] = b1; }
        if (n + 2 < ND) { f0[n + 2] = a2; f1[n + 2] = b2; }
        if (n + 3 < ND) { f0[n + 3] = a3; f1[n + 3] = b3; }
    }
    // last-block-done: the 180th data block to finish computes the prefix sums
    __threadfence();
    __syncthreads();
    if (tid == 0) last = atomicAdd((int*)ws, 1);
    __syncthreads();
    if (last != 179) return;
    __threadfence();
    float* buf = xs0;   // reuse LDS (all prior uses done; synced above)
    for (int q = 0; q < 4; ++q) {
        int b = q >> 1;
        int col = (q & 1) ? (ND - 1) : 0;
        float v = 0.f;
        if (tid < NA) v = ws[WS_FILT + (b * NA + tid) * ND + col];
        buf[tid] = v;
        __syncthreads();
        for (int off = 1; off < 256; off <<= 1) {
            float add = (tid >= off && tid - off < 192) ? buf[tid - off] : 0.f;
            __syncthreads();
            buf[tid] += add;
            __syncthreads();
        }
        int base = ((q & 1) ? WS_P728 : WS_P0) + b * 192;
        if (tid == 0) ws[base] = 0.f;
        if (tid < NA) ws[base + tid + 1] = buf[tid];
        __syncthreads();
    }
}

// Backprojection. idx(a) = clip(trunc((rot*c1)*729), 0, 728), rot = xc*cos+yc*sin.
// For r>=16 the angle axis splits into [low | band | high | band | low]:
//   high (idx=728): rot >= 6.27457  <=>  |a-phi| <= theta, theta = acos(6.27457/r)
//   low  (idx=0):   rot <  0.008619 <=>  |a-phi| >  ~pi/2
// Edges via atan2f/acosf (+-1 index guard, ~250x float-error margin); guarded
// band uses exact original arithmetic; clamped cores use prefix sums.
__global__ __launch_bounds__(256) void k_bp(const float* __restrict__ ws,
                                            float* __restrict__ out) {
    const float* __restrict__ tab = ws + WS_CS;
    int tid = threadIdx.x;
    int p = blockIdx.x * 256 + tid;
    int b = p / (HH * WW);
    int rem = p - b * (HH * WW);
    int y = rem / WW;
    int x = rem - y * WW;
    float xc = (float)x - (WW * 0.5f);
    float yc = (float)y - (HH * 0.5f);
    const float* f = ws + WS_FILT + b * (NA * ND);
    float acc = 0.f;
    float r2 = xc * xc + yc * yc;
    if (r2 < 256.0f) {
        for (int a = 0; a < NA; ++a) {
            float c = tab[2 * a], s = tab[2 * a + 1];
            float rot = xc * c + yc * s;
            float t = (rot * 0.15915494309189535f) * 729.0f;
            int i = (int)t;
            i = i < 0 ? 0 : (i > (ND - 1) ? (ND - 1) : i);
            acc += f[a * ND + i];
        }
    } else {
        float r = sqrtf(r2);
        float phi = atan2f(yc, xc);
        float cen = (phi < -1.5707964f) ? phi + 6.2831855f : phi;
        float theta = acosf(6.27457f / r);
        float tc = cen * 56.971835f;                 // *(179/pi)
        float w = theta * 56.971835f;
        int hs = (int)ceilf(tc - w) + 1;
        int he = (int)floorf(tc + w) - 1;
        int le = (int)floorf(tc - 89.5f) - 1;
        int rs = (int)ceilf(tc + 89.5f) + 1;
        hs = hs < 0 ? 0 : hs;
        he = he > (NA - 1) ? (NA - 1) : he;
        const float* P0 = ws + WS_P0 + b * 192;
        const float* P728 = ws + WS_P728 + b * 192;
        if (le >= 0) acc += P0[le + 1];
        if (rs <= NA - 1) acc += P0[NA] - P0[rs];
        if (he >= hs) acc += P728[he + 1] - P728[hs];
        int b1s = le + 1 < 0 ? 0 : le + 1;
        int b1e = hs - 1 > (NA - 1) ? (NA - 1) : hs - 1;
        int b2s = he + 1 < 0 ? 0 : he + 1;
        int b2e = rs - 1 > (NA - 1) ? (NA - 1) : rs - 1;
        for (int a = b1s; a <= b1e; ++a) {
            float c = tab[2 * a], s = tab[2 * a + 1];
            float rot = xc * c + yc * s;
            float t = (rot * 0.15915494309189535f) * 729.0f;
            int i = (int)t;
            i = i < 0 ? 0 : (i > (ND - 1) ? (ND - 1) : i);
            acc += f[a * ND + i];
        }
        for (int a = b2s; a <= b2e; ++a) {
            float c = tab[2 * a], s = tab[2 * a + 1];
            float rot = xc * c + yc * s;
            float t = (rot * 0.15915494309189535f) * 729.0f;
            int i = (int)t;
            i = i < 0 ? 0 : (i > (ND - 1) ? (ND - 1) : i);
            acc += f[a * ND + i];
        }
    }
    out[p] = fmaxf(acc * (float)(M_PI / NA), 0.0f);  // clip(.,0,max) == relu
}

extern "C" void kernel_launch(void* const* d_in, const int* in_sizes, int n_in,
                              void* d_out, int out_size, void* d_ws, size_t ws_size,
                              hipStream_t stream) {
    const float* sino = (const float*)d_in[0];
    float* out = (float*)d_out;
    float* ws = (float*)d_ws;

    hipMemsetAsync(ws, 0, 4, stream);   // zero the completion counter
    hipLaunchKernelGGL(k_filter, dim3(181), dim3(192), 0, stream, sino, ws);
    hipLaunchKernelGGL(k_bp, dim3((NB * HH * WW) / 256), dim3(256), 0, stream, ws, out);
}

// Round 6
// 107.582 us; speedup vs baseline: 1.1608x; 1.1608x over previous
//
#include <hip/hip_runtime.h>
#include <math.h>

#define HH 512
#define WW 512
#define NA 180
#define ND 729
#define NB 2

// ws layout (float units):
//   [1024, 1024+360)   interleaved {cos,sin} per angle
//   [2048 + b*192)     P0[b][0..180]   (exclusive prefix of f[b][a][0])
//   [2560 + b*192)     P728[b][0..180] (exclusive prefix of f[b][a][728])
//   [4096, ...)        filtered sinograms
#define WS_CS 1024
#define WS_P0 2048
#define WS_P728 2560
#define WS_FILT 4096

// Filter kernel (closed form):
//   g[n] = (0.125 + min(n, D-n)/1458) / 729   (tail of truncated odd-k sum < 7e-8/tap)
__device__ __forceinline__ float g_of(int n) {
    int m = n < (ND - n) ? n : (ND - n);
    return (float)((0.125 + (double)m * (1.0 / 1458.0)) * (1.0 / 729.0));
}

// Circular convolution: filtered[row][n] = sum_m x[row][m] * g[(n-m) mod D].
// Grid: 720 data blocks (blk = 2*row + side; side = output half) + 1 angle block.
// 192 threads: tid<96 -> m in [0,364), tid>=96 -> m in [364,732); each active
// thread does 4 outputs x 4 m's register-blocked (aligned b128 ga-window reads,
// n-m == 0 mod 4 always). Halves combined via LDS (deterministic order).
// __launch_bounds__(192,1): min-waves/EU=1 lifts VGPR budget -> no spill (the
// R5 2-row variant was allocated 24 VGPRs and spilled the hot loop to scratch).
__global__ __launch_bounds__(192, 1) void k_filter(const float* __restrict__ sino,
                                                   float* __restrict__ ws) {
    int blk = blockIdx.x;
    int tid = threadIdx.x;
    if (blk == 720) {   // angle tables
        for (int t = tid; t < NA; t += 192) {
            double ang = M_PI * (double)t / (double)(NA - 1);
            ws[WS_CS + 2 * t] = (float)cos(ang);
            ws[WS_CS + 2 * t + 1] = (float)sin(ang);
        }
        return;
    }
    int row = blk >> 1, side = blk & 1;
    __shared__ float xs[736];    // x zero-padded to 736
    __shared__ float ga[1464];   // ga[i] = g[(i+727) mod D]
    const float* x = sino + row * ND;
    for (int i = tid; i < 736; i += 192) xs[i] = (i < ND) ? x[i] : 0.0f;
    for (int i = tid; i < 1464; i += 192) ga[i] = g_of((i + 727) % ND);
    __syncthreads();
    int mh = tid / 96;               // m-half
    int t = tid - mh * 96;           // quad index within side
    int nq = side ? 91 : 92;         // quads on this side (side1 ends at n=728)
    bool active = t < nq;
    int n = 4 * (side * 92 + t);
    float a0 = 0.f, a1 = 0.f, a2 = 0.f, a3 = 0.f;
    if (active) {
        int m0 = mh ? 364 : 0;
        int m1 = mh ? 732 : 364;     // exclusive; xs[729..735]=0 keeps m=728 safe
        #pragma unroll 2
        for (int m = m0; m < m1; m += 4) {
            float4 xv = *(const float4*)&xs[m];       // broadcast
            int B = n - m + 728;                      // 4-aligned, in [0,1456]
            float4 gA = *(const float4*)&ga[B];       // w[0..3]
            float4 gB = *(const float4*)&ga[B + 4];   // w[4..7]
            // acc[dn] += sum_dm xv[dm] * w[3+dn-dm]
            a0 += xv.x * gA.w + xv.y * gA.z + xv.z * gA.y + xv.w * gA.x;
            a1 += xv.x * gB.x + xv.y * gA.w + xv.z * gA.z + xv.w * gA.y;
            a2 += xv.x * gB.y + xv.y * gB.x + xv.z * gA.w + xv.w * gA.z;
            a3 += xv.x * gB.z + xv.y * gB.y + xv.z * gB.x + xv.w * gA.w;
        }
    }
    __syncthreads();                 // all xs reads done; reuse xs as reduce buf
    if (mh == 1 && active) {
        float4 v; v.x = a0; v.y = a1; v.z = a2; v.w = a3;
        *(float4*)&xs[4 * t] = v;
    }
    __syncthreads();
    if (mh == 0 && active) {
        float4 v = *(const float4*)&xs[4 * t];
        a0 += v.x; a1 += v.y; a2 += v.z; a3 += v.w;
        float* f = ws + WS_FILT + row * ND;
        f[n] = a0;
        if (n + 1 < ND) f[n + 1] = a1;
        if (n + 2 < ND) f[n + 2] = a2;
        if (n + 3 < ND) f[n + 3] = a3;
    }
}

// Exclusive prefix sums of f[b][a][0] and f[b][a][728] over a. One block.
__global__ __launch_bounds__(256) void k_prefix(float* __restrict__ ws) {
    __shared__ float buf[256];
    int tid = threadIdx.x;
    for (int q = 0; q < 4; ++q) {
        int b = q >> 1;
        int col = (q & 1) ? (ND - 1) : 0;
        float v = 0.f;
        if (tid < NA) v = ws[WS_FILT + (b * NA + tid) * ND + col];
        buf[tid] = v;
        __syncthreads();
        for (int off = 1; off < 256; off <<= 1) {
            float add = (tid >= off) ? buf[tid - off] : 0.f;
            __syncthreads();
            buf[tid] += add;
            __syncthreads();
        }
        int base = ((q & 1) ? WS_P728 : WS_P0) + b * 192;
        if (tid == 0) ws[base] = 0.f;
        if (tid < NA) ws[base + tid + 1] = buf[tid];
        __syncthreads();
    }
}

// Backprojection. idx(a) = clip(trunc((rot*c1)*729), 0, 728), rot = xc*cos+yc*sin.
// For r>=16 the angle axis splits into [low | band | high | band | low]:
//   high (idx=728): rot >= 6.27457  <=>  |a-phi| <= theta, theta = acos(6.27457/r)
//   low  (idx=0):   rot <  0.008619 <=>  |a-phi| >  ~pi/2
// Edges via atan2f/acosf (+-1 index guard, ~250x float-error margin); guarded
// band uses exact original arithmetic; clamped cores use prefix sums.
__global__ __launch_bounds__(256) void k_bp(const float* __restrict__ ws,
                                            float* __restrict__ out) {
    const float* __restrict__ tab = ws + WS_CS;
    int tid = threadIdx.x;
    int p = blockIdx.x * 256 + tid;
    int b = p / (HH * WW);
    int rem = p - b * (HH * WW);
    int y = rem / WW;
    int x = rem - y * WW;
    float xc = (float)x - (WW * 0.5f);
    float yc = (float)y - (HH * 0.5f);
    const float* f = ws + WS_FILT + b * (NA * ND);
    float acc = 0.f;
    float r2 = xc * xc + yc * yc;
    if (r2 < 256.0f) {
        for (int a = 0; a < NA; ++a) {
            float c = tab[2 * a], s = tab[2 * a + 1];
            float rot = xc * c + yc * s;
            float t = (rot * 0.15915494309189535f) * 729.0f;
            int i = (int)t;
            i = i < 0 ? 0 : (i > (ND - 1) ? (ND - 1) : i);
            acc += f[a * ND + i];
        }
    } else {
        float r = sqrtf(r2);
        float phi = atan2f(yc, xc);
        float cen = (phi < -1.5707964f) ? phi + 6.2831855f : phi;
        float theta = acosf(6.27457f / r);
        float tc = cen * 56.971835f;                 // *(179/pi)
        float w = theta * 56.971835f;
        int hs = (int)ceilf(tc - w) + 1;
        int he = (int)floorf(tc + w) - 1;
        int le = (int)floorf(tc - 89.5f) - 1;
        int rs = (int)ceilf(tc + 89.5f) + 1;
        hs = hs < 0 ? 0 : hs;
        he = he > (NA - 1) ? (NA - 1) : he;
        const float* P0 = ws + WS_P0 + b * 192;
        const float* P728 = ws + WS_P728 + b * 192;
        if (le >= 0) acc += P0[le + 1];
        if (rs <= NA - 1) acc += P0[NA] - P0[rs];
        if (he >= hs) acc += P728[he + 1] - P728[hs];
        int b1s = le + 1 < 0 ? 0 : le + 1;
        int b1e = hs - 1 > (NA - 1) ? (NA - 1) : hs - 1;
        int b2s = he + 1 < 0 ? 0 : he + 1;
        int b2e = rs - 1 > (NA - 1) ? (NA - 1) : rs - 1;
        for (int a = b1s; a <= b1e; ++a) {
            float c = tab[2 * a], s = tab[2 * a + 1];
            float rot = xc * c + yc * s;
            float t = (rot * 0.15915494309189535f) * 729.0f;
            int i = (int)t;
            i = i < 0 ? 0 : (i > (ND - 1) ? (ND - 1) : i);
            acc += f[a * ND + i];
        }
        for (int a = b2s; a <= b2e; ++a) {
            float c = tab[2 * a], s = tab[2 * a + 1];
            float rot = xc * c + yc * s;
            float t = (rot * 0.15915494309189535f) * 729.0f;
            int i = (int)t;
            i = i < 0 ? 0 : (i > (ND - 1) ? (ND - 1) : i);
            acc += f[a * ND + i];
        }
    }
    out[p] = fmaxf(acc * (float)(M_PI / NA), 0.0f);  // clip(.,0,max) == relu
}

extern "C" void kernel_launch(void* const* d_in, const int* in_sizes, int n_in,
                              void* d_out, int out_size, void* d_ws, size_t ws_size,
                              hipStream_t stream) {
    const float* sino = (const float*)d_in[0];
    float* out = (float*)d_out;
    float* ws = (float*)d_ws;

    hipLaunchKernelGGL(k_filter, dim3(721), dim3(192), 0, stream, sino, ws);
    hipLaunchKernelGGL(k_prefix, dim3(1), dim3(256), 0, stream, ws);
    hipLaunchKernelGGL(k_bp, dim3((NB * HH * WW) / 256), dim3(256), 0, stream, ws, out);
}